// Round 5
// baseline (193.069 us; speedup 1.0000x reference)
//
#include <hip/hip_runtime.h>
#include <cstddef>
#include <cstdint>

// GMM E-step: N=200000, K=16, D=64, fp32 in/out.
// R10: estep switched to mfma_f32_32x32x16_f16: same FLOPs in HALF the MFMA
// instructions (384->192/wave) at the faster 32x32 rate (2382 vs 2075 TF
// ubench = -13% matrix-pipe time). R9 proved estep is issue-additive (VALU
// cuts land 1:1 in duration), so instruction-count cuts are the lever.
// tv now stored in 32x32 C-fragment register order: estep loads -t as one
// f32x16 (4x dwordx4) used directly as the first MFMA's C operand (zero
// movs). s_setprio(1) wraps the MFMA cluster (free-running waves = the
// phase-diverse regime where setprio pays). Precompute structure = R8/R9
// verified (single-wave register Cholesky + LDS handoff + register fwd-subst
// inverse); only its WA/tv output swizzles changed to the 32x32 layouts.
// C/D layout per verified m74/m101: col=lane&31, row=(reg&3)+8*(reg>>2)+
// 4*(lane>>5). A/B layout: row(col)=lane&31, k=(lane>>5)*8+u (same pattern
// as our verified 16x16x32 usage, K-groups of 8 by lane>>log2(M)).

#define GMM_D 64
#define GMM_K 16

typedef _Float16 half8 __attribute__((ext_vector_type(8)));
typedef float f32x4 __attribute__((ext_vector_type(4)));
typedef float f32x16 __attribute__((ext_vector_type(16)));

// ws: WA [16 comps][16 frags][64 lanes][8 f16] = 262144 B, then tv, cc (f32)
#define WA_BYTES (GMM_K * 16 * 64 * 8 * 2)

__device__ __forceinline__ float fast_rsqrt(float x) {
#if __has_builtin(__builtin_amdgcn_rsqf)
    // v_rsq_f32 (~1 ulp) + one Newton step -> full fp32 accuracy
    const float r = __builtin_amdgcn_rsqf(x);
    return r * (1.5f - 0.5f * x * r * r);
#else
    return 1.0f / sqrtf(x);
#endif
}

// broadcast lane l's value of v to all lanes (l compile-time after unroll)
__device__ __forceinline__ float lane_bcast(float v, int l) {
    return __int_as_float(__builtin_amdgcn_readlane(__float_as_int(v), l));
}

// ---------------------------------------------------------------------------
// Precompute: one WAVE (64 threads) per component (verified R8/R9 structure).
// Phase 1: register Cholesky via readlane broadcasts. Phase 2: register
// forward-substitution inverse fed by wave-uniform ds_read_b128 of L rows.
// At most one 64-float register array live at a time (R7 lesson).
// Epilogue swizzles updated for 32x32x16 fragments:
//   A-frag f = mt*8 + ks*2 + h (mt: 32-row tile, ks: K=16 step, h: hi/lo):
//     lane L elem u = Whl[mt*32 + (L&31)][ks*16 + (L>>5)*8 + u]
//   tv[k][mt][g][reg] = -t[mt*32 + 4g + (reg&3) + 8*(reg>>2)]  (C-reg order)
// ---------------------------------------------------------------------------
__global__ __launch_bounds__(64) void gmm_precompute_kernel(
    const float* __restrict__ pi, const float* __restrict__ mus,
    const float* __restrict__ covs, _Float16* __restrict__ WA,
    float* __restrict__ tv, float* __restrict__ cc)
{
    const int k = blockIdx.x;
    const int r = threadIdx.x;  // lane id

    __shared__ alignas(16) float Ls[GMM_D][68];  // L rows, upper tri zeroed;
                                                 // 272 B stride: 16B-aligned
    __shared__ float Wv[GMM_D][GMM_D + 1];       // W = L^{-1}, for epilogue

    // ---- load row r of Sigma into registers (16x float4, L2-resident) ----
    float A_r[GMM_D];
    {
        const float4* src = reinterpret_cast<const float4*>(
            covs + (size_t)k * GMM_D * GMM_D + (size_t)r * GMM_D);
        #pragma unroll
        for (int u = 0; u < GMM_D / 4; ++u) {
            const float4 v = src[u];
            A_r[4 * u + 0] = v.x; A_r[4 * u + 1] = v.y;
            A_r[4 * u + 2] = v.z; A_r[4 * u + 3] = v.w;
        }
    }

    // ---- Phase 1: register Cholesky, right-looking, zero barriers ----
    float mydiag = 1.0f, myrs = 1.0f;
    #pragma unroll
    for (int j = 0; j < GMM_D; ++j) {
        const float pivot = lane_bcast(A_r[j], j);   // lane j: valid diag
        const float rs = fast_rsqrt(pivot);
        const float valj = A_r[j] * rs;              // L[r][j]; lane j: sqrt(pivot)
        if (r == j) { mydiag = valj; myrs = rs; }
        A_r[j] = valj;
        #pragma unroll
        for (int p = j + 1; p < GMM_D; ++p)          // rank-1 trailing update
            A_r[p] -= valj * lane_bcast(valj, p);    // L[p][j] from lane p
    }

    // ---- handoff: dump L rows to LDS, upper triangle zeroed. A_r dies. ----
    #pragma unroll
    for (int p = 0; p < GMM_D; ++p)
        Ls[r][p] = (p <= r) ? A_r[p] : 0.0f;
    __syncthreads();   // single wave: cheap

    // ---- Phase 2: lane r solves L w = e_r; only w[64] live in registers ----
    float w[GMM_D];
    #pragma unroll
    for (int i = 0; i < GMM_D; ++i) w[i] = 0.0f;

    #pragma unroll
    for (int i = 0; i < GMM_D; ++i) {
        const f32x4* Lrow = reinterpret_cast<const f32x4*>(&Ls[i][0]);
        float a0 = 0.0f, a1 = 0.0f, a2 = 0.0f, a3 = 0.0f;
        #pragma unroll
        for (int u = 0; u <= (i >> 2); ++u) {        // zeros make tail exact
            const f32x4 lv = Lrow[u];
            a0 -= lv[0] * w[4 * u + 0];
            a1 -= lv[1] * w[4 * u + 1];
            a2 -= lv[2] * w[4 * u + 2];
            a3 -= lv[3] * w[4 * u + 3];
        }
        const float invd = lane_bcast(myrs, i);      // 1/L[i][i]
        const float dlt = (r == i) ? 1.0f : 0.0f;
        w[i] = (dlt + (a0 + a1) + (a2 + a3)) * invd;
    }

    // ---- dump W to LDS (lane r holds column r -> write transposed) ----
    #pragma unroll
    for (int i = 0; i < GMM_D; ++i)
        Wv[i][r] = w[i];          // consecutive addresses: conflict-free
    __syncthreads();

    // ---- tv = -(W mu), stored in 32x32 C-fragment register order ----
    // row r -> [k][mt=r>>5][g=(r>>2)&1][reg=(r&3)+4*((r>>3)&3)]
    {
        const float* mk = mus + k * GMM_D;
        float s0 = 0.f, s1 = 0.f, s2 = 0.f, s3 = 0.f;
        #pragma unroll
        for (int c = 0; c < GMM_D; c += 4) {
            s0 += Wv[r][c + 0] * mk[c + 0];
            s1 += Wv[r][c + 1] * mk[c + 1];
            s2 += Wv[r][c + 2] * mk[c + 2];
            s3 += Wv[r][c + 3] * mk[c + 3];
        }
        const int idx = (r >> 5) * 32 + ((r >> 2) & 1) * 16
                      + (r & 3) + 4 * ((r >> 3) & 3);
        tv[k * GMM_D + idx] = -((s0 + s1) + (s2 + s3));
    }

    // ---- swizzle W -> f16 hi/lo A-fragments for 32x32x16 ----
    // f = mt*8 + ks*2 + h: lane elem u = W[mt*32+(r&31)][ks*16+(r>>5)*8+u]
    {
        const int lr = r & 31, g = r >> 5;
        #pragma unroll
        for (int f = 0; f < 16; ++f) {
            const int mt = f >> 3, ks = (f >> 1) & 3, h = f & 1;
            const int row = mt * 32 + lr;
            const int db = ks * 16 + g * 8;
            half8 hv;
            #pragma unroll
            for (int u = 0; u < 8; ++u) {
                const float v = Wv[row][db + u];
                _Float16 hh = (_Float16)v;
                if (h) hh = (_Float16)(v - (float)hh);
                hv[u] = hh;
            }
            *(half8*)(WA + ((size_t)((k * 16 + f) * 64) + r) * 8) = hv;
        }
    }

    // ---- c_k = log pi_k - sum(log L_ii) - 0.5*D*log(2*pi) ----
    {
        float ll = logf(mydiag);
        #pragma unroll
        for (int off = 32; off > 0; off >>= 1) ll += __shfl_down(ll, off);
        if (r == 0)
            cc[k] = logf(pi[k]) - ll - 0.5f * 64.0f * 1.8378770664093453f;
    }
}

// ---------------------------------------------------------------------------
// E-step: block = 4 waves, 64 points; wave w owns comps 4w..4w+3.
// Per (comp, nt32): 2 Mtiles(32 rows) x 12 MFMA 32x32x16 f16 (hh + lh + hl
// over 4 K-steps), C preloaded with -t via f32x16 load, maha = 32 squares
// in-register + 1 shfl_xor(32).
// ---------------------------------------------------------------------------
__global__ __launch_bounds__(256) void gmm_estep_kernel(
    const float* __restrict__ X, const _Float16* __restrict__ WA,
    const float* __restrict__ tv, const float* __restrict__ cc,
    float* __restrict__ out, int N)
{
    // xs row (per point): [hi 0..63 | lo 0..63 | pad 8] f16 = 136 (272 B)
    __shared__ _Float16 xs[64 * 136];
    __shared__ float lg[64 * 17];

    const int tid = threadIdx.x;

    // ---- stage X -> f16 hi/lo in LDS: thread t: point t/4, dims (t%4)*16 ----
    {
        const int p = tid >> 2, qq = tid & 3;
        const int np = blockIdx.x * 64 + p;
        if (np < N) {
            const float4* src = reinterpret_cast<const float4*>(X + (size_t)np * GMM_D) + qq * 4;
            float vv[16];
            #pragma unroll
            for (int u = 0; u < 4; ++u) {
                const float4 v = src[u];
                vv[4 * u + 0] = v.x; vv[4 * u + 1] = v.y;
                vv[4 * u + 2] = v.z; vv[4 * u + 3] = v.w;
            }
            half8 h0, h1, l0, l1;
            #pragma unroll
            for (int u = 0; u < 8; ++u) {
                const _Float16 a = (_Float16)vv[u];
                const _Float16 b = (_Float16)vv[u + 8];
                h0[u] = a; l0[u] = (_Float16)(vv[u] - (float)a);
                h1[u] = b; l1[u] = (_Float16)(vv[u + 8] - (float)b);
            }
            _Float16* row = xs + p * 136;
            *(half8*)(row + qq * 16)          = h0;
            *(half8*)(row + qq * 16 + 8)      = h1;
            *(half8*)(row + 64 + qq * 16)     = l0;
            *(half8*)(row + 64 + qq * 16 + 8) = l1;
        }
    }
    __syncthreads();

    const int lane = tid & 63;
    const int wave = __builtin_amdgcn_readfirstlane(tid >> 6);
    const int pt32 = lane & 31;   // point within 32-tile = MFMA col
    const int g    = lane >> 5;   // K-group / C row-half selector

    #pragma unroll 1
    for (int kk = 0; kk < 4; ++kk) {
        const int k = wave * 4 + kk;  // wave-uniform

        // A fragments: 16 x global_load_dwordx4, coalesced, L2-resident.
        // af[mt][ks][h]: h=0 hi, h=1 lo.
        half8 af[2][4][2];
        const _Float16* wab = WA + (size_t)k * 8192 + lane * 8;
        #pragma unroll
        for (int mt = 0; mt < 2; ++mt)
            #pragma unroll
            for (int ks = 0; ks < 4; ++ks)
                #pragma unroll
                for (int h = 0; h < 2; ++h)
                    af[mt][ks][h] = *(const half8*)(wab + (mt * 8 + ks * 2 + h) * 512);

        // -t in C-fragment register order: one f32x16 per Mtile (4x dwordx4)
        f32x16 t16[2];
        #pragma unroll
        for (int mt = 0; mt < 2; ++mt)
            t16[mt] = *(const f32x16*)(tv + k * 64 + mt * 32 + g * 16);

        #pragma unroll 1
        for (int nt = 0; nt < 2; ++nt) {
            const _Float16* xrow = xs + (nt * 32 + pt32) * 136 + g * 8;
            half8 bh[4];
            #pragma unroll
            for (int ks = 0; ks < 4; ++ks)
                bh[ks] = *(const half8*)(xrow + ks * 16);        // hi, k-step ks

            __builtin_amdgcn_s_setprio(1);
            f32x16 c0 = __builtin_amdgcn_mfma_f32_32x32x16_f16(af[0][0][0], bh[0], t16[0], 0, 0, 0);
            f32x16 c1 = __builtin_amdgcn_mfma_f32_32x32x16_f16(af[1][0][0], bh[0], t16[1], 0, 0, 0);
            #pragma unroll
            for (int ks = 1; ks < 4; ++ks) {                     // hi*hi
                c0 = __builtin_amdgcn_mfma_f32_32x32x16_f16(af[0][ks][0], bh[ks], c0, 0, 0, 0);
                c1 = __builtin_amdgcn_mfma_f32_32x32x16_f16(af[1][ks][0], bh[ks], c1, 0, 0, 0);
            }
            #pragma unroll
            for (int ks = 0; ks < 4; ++ks) {                     // lo_W*hi_X
                c0 = __builtin_amdgcn_mfma_f32_32x32x16_f16(af[0][ks][1], bh[ks], c0, 0, 0, 0);
                c1 = __builtin_amdgcn_mfma_f32_32x32x16_f16(af[1][ks][1], bh[ks], c1, 0, 0, 0);
            }
            half8 bl[4];
            #pragma unroll
            for (int ks = 0; ks < 4; ++ks)
                bl[ks] = *(const half8*)(xrow + 64 + ks * 16);   // lo, k-step ks
            #pragma unroll
            for (int ks = 0; ks < 4; ++ks) {                     // hi_W*lo_X
                c0 = __builtin_amdgcn_mfma_f32_32x32x16_f16(af[0][ks][0], bl[ks], c0, 0, 0, 0);
                c1 = __builtin_amdgcn_mfma_f32_32x32x16_f16(af[1][ks][0], bl[ks], c1, 0, 0, 0);
            }
            __builtin_amdgcn_s_setprio(0);

            // maha: 32 squares (rows this lane holds) + 1 xor(32) for the rest
            float s0 = 0.f, s1 = 0.f, s2 = 0.f, s3 = 0.f;
            #pragma unroll
            for (int u = 0; u < 16; u += 4) {
                s0 += c0[u + 0] * c0[u + 0] + c1[u + 0] * c1[u + 0];
                s1 += c0[u + 1] * c0[u + 1] + c1[u + 1] * c1[u + 1];
                s2 += c0[u + 2] * c0[u + 2] + c1[u + 2] * c1[u + 2];
                s3 += c0[u + 3] * c0[u + 3] + c1[u + 3] * c1[u + 3];
            }
            float mahaP = (s0 + s1) + (s2 + s3);
            mahaP += __shfl_xor(mahaP, 32);
            if (g == 0 && (blockIdx.x * 64 + nt * 32 + pt32) < N)
                lg[(nt * 32 + pt32) * 17 + k] = cc[k] - 0.5f * mahaP;
        }
    }
    __syncthreads();

    // softmax: 4 threads/point, one float4 each (contiguous stores)
    {
        const int p = tid >> 2, qq = tid & 3;
        const int np = blockIdx.x * 64 + p;
        if (np < N) {
            const float* row = &lg[p * 17];
            float m = row[0];
            #pragma unroll
            for (int j = 1; j < GMM_K; ++j) m = fmaxf(m, row[j]);
            float e[GMM_K];
            float s = 0.0f;
            #pragma unroll
            for (int j = 0; j < GMM_K; ++j) { e[j] = __expf(row[j] - m); s += e[j]; }
            const float inv = 1.0f / s;
            float4 v;
            v.x = e[qq * 4 + 0] * inv;
            v.y = e[qq * 4 + 1] * inv;
            v.z = e[qq * 4 + 2] * inv;
            v.w = e[qq * 4 + 3] * inv;
            reinterpret_cast<float4*>(out + (size_t)np * GMM_K)[qq] = v;
        }
    }
}

// ---------------------------------------------------------------------------
extern "C" void kernel_launch(void* const* d_in, const int* in_sizes, int n_in,
                              void* d_out, int out_size, void* d_ws, size_t ws_size,
                              hipStream_t stream)
{
    const float* X    = (const float*)d_in[0];
    const float* pi   = (const float*)d_in[1];
    const float* mus  = (const float*)d_in[2];
    const float* covs = (const float*)d_in[3];
    float* out = (float*)d_out;

    const int N = in_sizes[0] / GMM_D;

    _Float16* WA = (_Float16*)d_ws;
    float* tv = (float*)((char*)d_ws + WA_BYTES);
    float* cc = tv + GMM_K * GMM_D;

    gmm_precompute_kernel<<<dim3(GMM_K), dim3(64), 0, stream>>>(pi, mus, covs, WA, tv, cc);

    const int blocks = (N + 63) / 64;  // 200000/64 = 3125 exactly
    gmm_estep_kernel<<<dim3(blocks), dim3(256), 0, stream>>>(X, WA, tv, cc, out, N);
}